// Round 8
// baseline (46004.614 us; speedup 1.0000x reference)
//
#include <hip/hip_runtime.h>
#include <cmath>

// Problem constants
#define T_STEPS 16384
#define D_IN    257
#define H_DIM   512
#define O_DIM   257
#define G4      2048   // 4*H

typedef unsigned long long u64;

// Workspace layout (bytes):
//   [0, 8192)    : u64 msg[2][512]  (double-buffered self-validating h msgs)
//                  msg word i = (tag << 32) | float_bits(h[i])
//   [8192, ...)  : float x_gates[T][2048]
//   then         : float hs[T][512]
#define WS_XG_OFF     8192
#define WS_HS_OFF     (8192 + (size_t)T_STEPS * G4 * 4)

__device__ inline float fast_sigmoid(float x) {
    return 1.f / (1.f + __expf(-x));
}
__device__ inline float fast_tanh(float x) {
    float ax = fminf(fabsf(x), 15.f);
    float e  = __expf(2.f * ax);
    float t  = (e - 1.f) / (e + 1.f);
    return copysignf(t, x);
}
__device__ inline float dot4(float4 a, float4 b) {
    return a.x * b.x + a.y * b.y + a.z * b.z + a.w * b.w;
}

// ---------------------------------------------------------------------------
// Phase 1: x_gates[t][j] = sum_k stft[t][k] * W_ih[j][k] + (b_ih[j]+b_hh[j])
// ---------------------------------------------------------------------------
__global__ __launch_bounds__(256) void xgate_gemm(
    const float* __restrict__ stft, const float* __restrict__ W_ih,
    const float* __restrict__ b_ih, const float* __restrict__ b_hh,
    float* __restrict__ xg)
{
    const int tid = threadIdx.x;
    const int tx = tid & 15, ty = tid >> 4;
    const int j0 = blockIdx.x * 64;
    const int t0 = blockIdx.y * 64;

    __shared__ float s_a[64][17];
    __shared__ float s_b[64][17];

    float acc[4][4] = {};

    for (int k0 = 0; k0 < D_IN; k0 += 16) {
        #pragma unroll
        for (int l = 0; l < 4; ++l) {
            int idx = tid + l * 256;
            int r  = idx >> 4;
            int kk = idx & 15;
            int k  = k0 + kk;
            s_a[r][kk] = (k < D_IN) ? stft[(size_t)(t0 + r) * D_IN + k] : 0.f;
            s_b[r][kk] = (k < D_IN) ? W_ih[(size_t)(j0 + r) * D_IN + k] : 0.f;
        }
        __syncthreads();
        #pragma unroll
        for (int kk = 0; kk < 16; ++kk) {
            float a[4], b[4];
            #pragma unroll
            for (int r = 0; r < 4; ++r) a[r] = s_a[ty * 4 + r][kk];
            #pragma unroll
            for (int c = 0; c < 4; ++c) b[c] = s_b[tx * 4 + c][kk];
            #pragma unroll
            for (int r = 0; r < 4; ++r)
                #pragma unroll
                for (int c = 0; c < 4; ++c)
                    acc[r][c] += a[r] * b[c];
        }
        __syncthreads();
    }

    float bias[4];
    #pragma unroll
    for (int c = 0; c < 4; ++c) {
        int j = j0 + tx * 4 + c;
        bias[c] = b_ih[j] + b_hh[j];
    }
    #pragma unroll
    for (int r = 0; r < 4; ++r) {
        int t = t0 + ty * 4 + r;
        #pragma unroll
        for (int c = 0; c < 4; ++c) {
            xg[(size_t)t * G4 + j0 + tx * 4 + c] = acc[r][c] + bias[c];
        }
    }
}

// ---------------------------------------------------------------------------
// Phase 2: persistent sequential LSTM (R7 matvec + speculative poll +
// distributed tail).
// 32 blocks x 512 threads (8 waves). Block g owns h[16g..16g+16) -> 64 rows.
// Wave w owns col chunk [64w, 64w+64) for the matvec; lane l = 4*j + c:
//   j = l>>2 (h-index within block), c = l&3 (16-col sub-chunk); each lane
//   computes all 4 gate partials of h-index j over its 16 cols (4 b128
//   broadcast reads, 64 weights in registers), 3-shuffle exchange butterfly.
// Speculative poll: the t+1 message load is issued BEFORE the barrier so its
// RTT overlaps matvec + tail; at the next loop top it usually hits first try.
// Distributed tail: wave w owns h-indices {2w, 2w+1}: after the single
// lgkm-only barrier it reduces its 8 rows from s_part (1 ds_read_b32/lane,
// 3 shfl_xor rounds), computes both c-states wave-replicated, and lanes 0/1
// publish the 2 self-validating 8B messages. No central wave0 serialization.
// ---------------------------------------------------------------------------
__global__ __launch_bounds__(512, 1) void lstm_seq(
    const float* __restrict__ W_hh, const float* __restrict__ xg,
    float* __restrict__ hs, u64* msg)
{
    const int tid  = threadIdx.x;        // 0..511
    const int g    = blockIdx.x;         // 0..31
    const int w    = tid >> 6;           // wave id = col chunk 0..7
    const int lane = tid & 63;
    const int j    = lane >> 2;          // 0..15 h-index within block (matvec)
    const int c    = lane & 3;           // 0..3 16-col sub-chunk (matvec)
    const int colb = w * 64 + c * 16;    // this lane's col base

    // Weights: all 4 gate rows of h-index (g*16+j), 16 cols each.
    const float* wbase = W_hh + (size_t)(g * 16 + j) * H_DIM + colb;
    const size_t gstride = (size_t)H_DIM * H_DIM;  // 512*512 between gates
    float4 wA0, wA1, wA2, wA3, wB0, wB1, wB2, wB3;
    float4 wC0, wC1, wC2, wC3, wD0, wD1, wD2, wD3;
    {
        const float4* p0 = (const float4*)(wbase);
        const float4* p1 = (const float4*)(wbase + gstride);
        const float4* p2 = (const float4*)(wbase + 2 * gstride);
        const float4* p3 = (const float4*)(wbase + 3 * gstride);
        wA0 = p0[0]; wA1 = p0[1]; wA2 = p0[2]; wA3 = p0[3];
        wB0 = p1[0]; wB1 = p1[1]; wB2 = p1[2]; wB3 = p1[3];
        wC0 = p2[0]; wC1 = p2[1]; wC2 = p2[2]; wC3 = p2[3];
        wD0 = p3[0]; wD1 = p3[1]; wD2 = p3[2]; wD3 = p3[3];
    }

    __shared__ float s_h[512];           // wave w stages+reads [64w,64w+64) only
    __shared__ float s_part[2][512];     // [t&1][w*64 + c*16 + j]

    u64* slot0 = msg;
    u64* slot1 = msg + 512;

    // Tail mapping: group rr = lane>>3 (0..7) -> gate = rr>>1, hh = rr&1;
    // this wave's h-indices are 2w and 2w+1.
    const int rr    = lane >> 3;
    const int gateT = rr >> 1;
    const int hhT   = rr & 1;
    const int rowT  = gateT * 16 + 2 * w + hhT;   // local row in [0,64)

    float c_st0 = 0.f, c_st1 = 0.f;      // states for h 2w, 2w+1 (replicated)

    // Prime the speculative poll for t=0.
    u64 u_spec = __hip_atomic_load(slot0 + tid, __ATOMIC_RELAXED,
                                   __HIP_MEMORY_SCOPE_AGENT);

    for (int t = 0; t < T_STEPS; ++t) {
        const unsigned tagt = (unsigned)t;
        const int buf = t & 1;

        // Distributed xg prefetch: every lane loads the value for its tail
        // row (8 unique dwords/wave, replicated within 8-lane groups).
        float xv = xg[(size_t)t * G4 + gateT * H_DIM + g * 16 + 2 * w + hhT];

        // Check the speculative load first; repoll only if stale.
        u64* rp = (buf ? slot1 : slot0) + tid;
        u64 u = u_spec;
        while ((unsigned)(u >> 32) != tagt) {
            u = __hip_atomic_load(rp, __ATOMIC_RELAXED, __HIP_MEMORY_SCOPE_AGENT);
        }

        // Intra-wave h staging: wave w only touches its own 64-word region.
        s_h[tid] = __uint_as_float((unsigned)u);

        // Issue next step's speculative poll NOW — its RTT overlaps the
        // matvec, barrier, and tail below.
        u_spec = __hip_atomic_load(((buf ^ 1) ? slot1 : slot0) + tid,
                                   __ATOMIC_RELAXED, __HIP_MEMORY_SCOPE_AGENT);

        // h slice for this lane: 16 floats (4x b128, broadcast across j).
        const float4* hv = (const float4*)(s_h + colb);
        float4 h0 = hv[0], h1 = hv[1], h2 = hv[2], h3 = hv[3];

        // 4 gate partials over this lane's 16 cols.
        float p0 = dot4(wA0, h0) + dot4(wA1, h1) + dot4(wA2, h2) + dot4(wA3, h3);
        float p1 = dot4(wB0, h0) + dot4(wB1, h1) + dot4(wB2, h2) + dot4(wB3, h3);
        float p2 = dot4(wC0, h0) + dot4(wC1, h1) + dot4(wC2, h2) + dot4(wC3, h3);
        float p3 = dot4(wD0, h0) + dot4(wD1, h1) + dot4(wD2, h2) + dot4(wD3, h3);

        // Exchange-half butterfly over the 4 c-lanes: lane c ends with the
        // full 64-col sum of gate c. 3 shuffles total.
        const bool lo2 = (c < 2);
        float a0 = (lo2 ? p0 : p2) + __shfl_xor(lo2 ? p2 : p0, 2, 64);
        float a1 = (lo2 ? p1 : p3) + __shfl_xor(lo2 ? p3 : p1, 2, 64);
        const bool ev = ((c & 1) == 0);
        float fin = (ev ? a0 : a1) + __shfl_xor(ev ? a1 : a0, 1, 64);

        // Write this wave's partial for row (gate=c, j): 2-way banks = free.
        s_part[buf][w * 64 + c * 16 + j] = fin;

        // lgkm-only barrier: LDS writes visible; NO vmcnt drain (publish
        // stores, xg loads, and the speculative poll stay in flight).
        asm volatile("s_waitcnt lgkmcnt(0)\n\ts_barrier" ::: "memory");

        // ---- Distributed tail: this wave finishes h-indices 2w, 2w+1 ----
        // Lane (rr, kk): read partial kk of row rowT; butterfly over kk.
        float sum = s_part[buf][(lane & 7) * 64 + rowT];
        sum += __shfl_xor(sum, 1, 64);
        sum += __shfl_xor(sum, 2, 64);
        sum += __shfl_xor(sum, 4, 64);
        float total = sum + xv;          // row total, replicated in 8-lane group

        // Gather the 8 gate totals (2 h-indices x 4 gates) wave-wide.
        float gi0 = __shfl(total, 0,  64), gi1 = __shfl(total, 8,  64);
        float gf0 = __shfl(total, 16, 64), gf1 = __shfl(total, 24, 64);
        float gg0 = __shfl(total, 32, 64), gg1 = __shfl(total, 40, 64);
        float go0 = __shfl(total, 48, 64), go1 = __shfl(total, 56, 64);

        float iv0 = fast_sigmoid(gi0), iv1 = fast_sigmoid(gi1);
        float fv0 = fast_sigmoid(gf0), fv1 = fast_sigmoid(gf1);
        float ov0 = fast_sigmoid(go0), ov1 = fast_sigmoid(go1);
        float gv0 = fast_tanh(gg0),    gv1 = fast_tanh(gg1);
        c_st0 = fv0 * c_st0 + iv0 * gv0;
        c_st1 = fv1 * c_st1 + iv1 * gv1;
        float hn0 = ov0 * fast_tanh(c_st0);
        float hn1 = ov1 * fast_tanh(c_st1);

        if (lane < 2) {
            float hn = (lane == 0) ? hn0 : hn1;
            const int hidx = g * 16 + 2 * w + lane;
            hs[(size_t)t * H_DIM + hidx] = hn;
            u64 m = ((u64)(tagt + 1) << 32) | (u64)__float_as_uint(hn);
            u64* wp = (((t + 1) & 1) ? slot1 : slot0) + hidx;
            __hip_atomic_store(wp, m, __ATOMIC_RELAXED, __HIP_MEMORY_SCOPE_AGENT);
        }
        // No trailing barrier: s_h is intra-wave; s_part double-buffered —
        // its re-write at t+2 is gated by the barrier at t+1, which every
        // wave only reaches after finishing its step-t s_part reads.
    }
}

// ---------------------------------------------------------------------------
// Phase 3: out = log_softmax(hs @ W_out^T + b_out)
// ---------------------------------------------------------------------------
__global__ __launch_bounds__(256) void out_softmax(
    const float* __restrict__ hs, const float* __restrict__ W_out,
    const float* __restrict__ b_out, float* __restrict__ out)
{
    const int tid = threadIdx.x;
    const int t0  = blockIdx.x * 16;

    __shared__ float s_w[257 * 33];
    __shared__ float s_hs[16 * 33];
    __shared__ float s_o[16 * 257];
    __shared__ float s_red[8];

    float acc[16] = {};
    float acc256 = 0.f;

    for (int k0 = 0; k0 < H_DIM; k0 += 32) {
        for (int idx = tid; idx < 257 * 32; idx += 256) {
            int row = idx >> 5, col = idx & 31;
            s_w[row * 33 + col] = W_out[(size_t)row * H_DIM + k0 + col];
        }
        for (int idx = tid; idx < 16 * 32; idx += 256) {
            int row = idx >> 5, col = idx & 31;
            s_hs[row * 33 + col] = hs[(size_t)(t0 + row) * H_DIM + k0 + col];
        }
        __syncthreads();
        #pragma unroll
        for (int kk = 0; kk < 32; ++kk) {
            float w = s_w[tid * 33 + kk];
            #pragma unroll
            for (int r = 0; r < 16; ++r)
                acc[r] += s_hs[r * 33 + kk] * w;
        }
        if (tid < 16) {
            #pragma unroll
            for (int kk = 0; kk < 32; ++kk)
                acc256 += s_w[256 * 33 + kk] * s_hs[tid * 33 + kk];
        }
        __syncthreads();
    }

    float bias_c = b_out[tid];
    #pragma unroll
    for (int r = 0; r < 16; ++r) s_o[r * 257 + tid] = acc[r] + bias_c;
    if (tid < 16) s_o[tid * 257 + 256] = acc256 + b_out[256];
    __syncthreads();

    const int lane = tid & 63, wid = tid >> 6;
    for (int r = 0; r < 16; ++r) {
        float v  = s_o[r * 257 + tid];
        float vx = (tid == 0) ? s_o[r * 257 + 256] : -INFINITY;
        float m = fmaxf(v, vx);
        #pragma unroll
        for (int off = 32; off > 0; off >>= 1) m = fmaxf(m, __shfl_xor(m, off, 64));
        if (lane == 0) s_red[wid] = m;
        __syncthreads();
        m = fmaxf(fmaxf(s_red[0], s_red[1]), fmaxf(s_red[2], s_red[3]));
        float e = expf(v - m) + ((tid == 0) ? expf(vx - m) : 0.f);
        #pragma unroll
        for (int off = 32; off > 0; off >>= 1) e += __shfl_xor(e, off, 64);
        if (lane == 0) s_red[4 + wid] = e;
        __syncthreads();
        float s = s_red[4] + s_red[5] + s_red[6] + s_red[7];
        float lg = logf(s) + m;
        out[(size_t)(t0 + r) * O_DIM + tid] = v - lg;
        if (tid == 0) out[(size_t)(t0 + r) * O_DIM + 256] = vx - lg;
    }
}

// ---------------------------------------------------------------------------
extern "C" void kernel_launch(void* const* d_in, const int* in_sizes, int n_in,
                              void* d_out, int out_size, void* d_ws, size_t ws_size,
                              hipStream_t stream) {
    (void)in_sizes; (void)n_in; (void)out_size; (void)ws_size;

    const float* stft  = (const float*)d_in[0];
    const float* W_ih  = (const float*)d_in[1];
    const float* W_hh  = (const float*)d_in[2];
    const float* b_ih  = (const float*)d_in[3];
    const float* b_hh  = (const float*)d_in[4];
    const float* W_out = (const float*)d_in[5];
    const float* b_out = (const float*)d_in[6];
    float* out = (float*)d_out;

    char* ws = (char*)d_ws;
    u64* msg  = (u64*)ws;
    float* xg = (float*)(ws + WS_XG_OFF);
    float* hs = (float*)(ws + WS_HS_OFF);

    // Zero both msg slots (ws is re-poisoned to 0xAA before every launch).
    // tag 0 + h 0 is exactly the t=0 initial state.
    (void)hipMemsetAsync(ws, 0, 8192, stream);

    xgate_gemm<<<dim3(G4 / 64, T_STEPS / 64), 256, 0, stream>>>(
        stft, W_ih, b_ih, b_hh, xg);
    lstm_seq<<<32, 512, 0, stream>>>(W_hh, xg, hs, msg);
    out_softmax<<<T_STEPS / 16, 256, 0, stream>>>(hs, W_out, b_out, out);
}

// Round 9
// 24690.350 us; speedup vs baseline: 1.8633x; 1.8633x over previous
//
#include <hip/hip_runtime.h>
#include <cmath>

// Problem constants
#define T_STEPS 16384
#define D_IN    257
#define H_DIM   512
#define O_DIM   257
#define G4      2048   // 4*H

typedef unsigned long long u64;

// Workspace layout (bytes):
//   [0, 8192)    : u64 msg[2][512]  (double-buffered self-validating h msgs)
//                  msg word i = (tag << 32) | float_bits(h[i])
//   [8192, ...)  : float x_gates[T][2048]
//   then         : float hs[T][512]
#define WS_XG_OFF     8192
#define WS_HS_OFF     (8192 + (size_t)T_STEPS * G4 * 4)

__device__ inline float fast_sigmoid(float x) {
    return 1.f / (1.f + __expf(-x));
}
__device__ inline float fast_tanh(float x) {
    float ax = fminf(fabsf(x), 15.f);
    float e  = __expf(2.f * ax);
    float t  = (e - 1.f) / (e + 1.f);
    return copysignf(t, x);
}
__device__ inline float dot4(float4 a, float4 b) {
    return a.x * b.x + a.y * b.y + a.z * b.z + a.w * b.w;
}

// Register pin: marks the value as asm-modified so the compiler cannot
// legally rematerialize the (const __restrict__) weight loads inside the
// loop — forces true register residency across the K-loop's memory clobbers.
#define PIN4(v) asm volatile("" : "+v"(v.x), "+v"(v.y), "+v"(v.z), "+v"(v.w))

// ---------------------------------------------------------------------------
// Phase 1: x_gates[t][j] = sum_k stft[t][k] * W_ih[j][k] + (b_ih[j]+b_hh[j])
// ---------------------------------------------------------------------------
__global__ __launch_bounds__(256) void xgate_gemm(
    const float* __restrict__ stft, const float* __restrict__ W_ih,
    const float* __restrict__ b_ih, const float* __restrict__ b_hh,
    float* __restrict__ xg)
{
    const int tid = threadIdx.x;
    const int tx = tid & 15, ty = tid >> 4;
    const int j0 = blockIdx.x * 64;
    const int t0 = blockIdx.y * 64;

    __shared__ float s_a[64][17];
    __shared__ float s_b[64][17];

    float acc[4][4] = {};

    for (int k0 = 0; k0 < D_IN; k0 += 16) {
        #pragma unroll
        for (int l = 0; l < 4; ++l) {
            int idx = tid + l * 256;
            int r  = idx >> 4;
            int kk = idx & 15;
            int k  = k0 + kk;
            s_a[r][kk] = (k < D_IN) ? stft[(size_t)(t0 + r) * D_IN + k] : 0.f;
            s_b[r][kk] = (k < D_IN) ? W_ih[(size_t)(j0 + r) * D_IN + k] : 0.f;
        }
        __syncthreads();
        #pragma unroll
        for (int kk = 0; kk < 16; ++kk) {
            float a[4], b[4];
            #pragma unroll
            for (int r = 0; r < 4; ++r) a[r] = s_a[ty * 4 + r][kk];
            #pragma unroll
            for (int c = 0; c < 4; ++c) b[c] = s_b[tx * 4 + c][kk];
            #pragma unroll
            for (int r = 0; r < 4; ++r)
                #pragma unroll
                for (int c = 0; c < 4; ++c)
                    acc[r][c] += a[r] * b[c];
        }
        __syncthreads();
    }

    float bias[4];
    #pragma unroll
    for (int c = 0; c < 4; ++c) {
        int j = j0 + tx * 4 + c;
        bias[c] = b_ih[j] + b_hh[j];
    }
    #pragma unroll
    for (int r = 0; r < 4; ++r) {
        int t = t0 + ty * 4 + r;
        #pragma unroll
        for (int c = 0; c < 4; ++c) {
            xg[(size_t)t * G4 + j0 + tx * 4 + c] = acc[r][c] + bias[c];
        }
    }
}

// ---------------------------------------------------------------------------
// Phase 2: persistent sequential LSTM (R7 structure + pinned weights +
// nontemporal streaming).
// 32 blocks x 512 threads (8 waves). Block g owns h[16g..16g+16) -> 64 rows.
// Wave w owns col chunk [64w, 64w+64); lane l = 4*j + c:
//   j = l>>2 (h-index within block), c = l&3 (16-col sub-chunk); each lane
//   computes all 4 gate partials of h-index j over its 16 cols (4 b128
//   broadcast reads, 64 weights PINNED in registers), 3-shuffle butterfly.
// ONE lgkm-only barrier per step (no vmcnt drain). Wave 0 sums the 8
// wave-partials per row, gathers gates in-wave, activates, publishes h via
// 16 coalesced 8B agent-scope self-validating messages. xg loads and hs
// stores are nontemporal so the streams don't evict msg lines from LLC.
// ---------------------------------------------------------------------------
__global__ __launch_bounds__(512, 1) void lstm_seq(
    const float* __restrict__ W_hh, const float* __restrict__ xg,
    float* __restrict__ hs, u64* __restrict__ msg)
{
    const int tid  = threadIdx.x;        // 0..511
    const int g    = blockIdx.x;         // 0..31
    const int w    = tid >> 6;           // wave id = col chunk 0..7
    const int lane = tid & 63;
    const int j    = lane >> 2;          // 0..15 h-index within block
    const int c    = lane & 3;           // 0..3 16-col sub-chunk
    const int colb = w * 64 + c * 16;    // this lane's col base

    // Weights: all 4 gate rows of h-index (g*16+j), 16 cols each.
    const float* wbase = W_hh + (size_t)(g * 16 + j) * H_DIM + colb;
    const size_t gstride = (size_t)H_DIM * H_DIM;  // 512*512 between gates
    float4 wA0, wA1, wA2, wA3, wB0, wB1, wB2, wB3;
    float4 wC0, wC1, wC2, wC3, wD0, wD1, wD2, wD3;
    {
        const float4* p0 = (const float4*)(wbase);
        const float4* p1 = (const float4*)(wbase + gstride);
        const float4* p2 = (const float4*)(wbase + 2 * gstride);
        const float4* p3 = (const float4*)(wbase + 3 * gstride);
        wA0 = p0[0]; wA1 = p0[1]; wA2 = p0[2]; wA3 = p0[3];
        wB0 = p1[0]; wB1 = p1[1]; wB2 = p1[2]; wB3 = p1[3];
        wC0 = p2[0]; wC1 = p2[1]; wC2 = p2[2]; wC3 = p2[3];
        wD0 = p3[0]; wD1 = p3[1]; wD2 = p3[2]; wD3 = p3[3];
    }
    // Pin: forbid rematerialization — weights stay in VGPRs for the whole loop.
    PIN4(wA0); PIN4(wA1); PIN4(wA2); PIN4(wA3);
    PIN4(wB0); PIN4(wB1); PIN4(wB2); PIN4(wB3);
    PIN4(wC0); PIN4(wC1); PIN4(wC2); PIN4(wC3);
    PIN4(wD0); PIN4(wD1); PIN4(wD2); PIN4(wD3);

    __shared__ float s_h[512];           // wave w stages+reads [64w,64w+64) only
    __shared__ float s_part[2][512];     // [t&1][w*64 + c*16 + j]

    u64* slot0 = msg;
    u64* slot1 = msg + 512;

    float c_state = 0.f;                 // wave0: state for j'=lane&15 (x4 repl)
    const int t_j = lane & 15;           // wave0 tail: h-index within block

    for (int t = 0; t < T_STEPS; ++t) {
        const unsigned tagt = (unsigned)t;
        const int buf = t & 1;

        // Wave 0 prefetches x_gates (independent of h) before the spin.
        // Nontemporal: read-once stream must not evict msg lines from LLC.
        float xv = 0.f;
        if (w == 0)
            xv = __builtin_nontemporal_load(
                xg + (size_t)t * G4 + (lane >> 4) * H_DIM + g * 16 + t_j);

        // Poll own single message word: tag==t validates payload in-load.
        u64* rp = (buf ? slot1 : slot0) + tid;
        u64 u;
        for (;;) {
            u = __hip_atomic_load(rp, __ATOMIC_RELAXED, __HIP_MEMORY_SCOPE_AGENT);
            if ((unsigned)(u >> 32) == tagt) break;
        }

        // Intra-wave h staging: wave w only touches its own 64-word region.
        s_h[tid] = __uint_as_float((unsigned)u);

        // h slice for this lane: 16 floats (4x b128, broadcast across j).
        const float4* hv = (const float4*)(s_h + colb);
        float4 h0 = hv[0], h1 = hv[1], h2 = hv[2], h3 = hv[3];

        // 4 gate partials over this lane's 16 cols (weights in registers).
        float p0 = dot4(wA0, h0) + dot4(wA1, h1) + dot4(wA2, h2) + dot4(wA3, h3);
        float p1 = dot4(wB0, h0) + dot4(wB1, h1) + dot4(wB2, h2) + dot4(wB3, h3);
        float p2 = dot4(wC0, h0) + dot4(wC1, h1) + dot4(wC2, h2) + dot4(wC3, h3);
        float p3 = dot4(wD0, h0) + dot4(wD1, h1) + dot4(wD2, h2) + dot4(wD3, h3);

        // Exchange-half butterfly over the 4 c-lanes: lane c ends with the
        // full 64-col sum of gate c. 3 shuffles total.
        const bool lo2 = (c < 2);
        float a0 = (lo2 ? p0 : p2) + __shfl_xor(lo2 ? p2 : p0, 2, 64);
        float a1 = (lo2 ? p1 : p3) + __shfl_xor(lo2 ? p3 : p1, 2, 64);
        const bool ev = ((c & 1) == 0);
        float fin = (ev ? a0 : a1) + __shfl_xor(ev ? a1 : a0, 1, 64);

        // Write this wave's partial for row (gate=c, j): 2-way banks = free.
        s_part[buf][w * 64 + c * 16 + j] = fin;

        // lgkm-only barrier: LDS writes visible; NO vmcnt drain (publish
        // stores and xg loads stay in flight).
        asm volatile("s_waitcnt lgkmcnt(0)\n\ts_barrier" ::: "memory");

        if (w == 0) {
            // Sum the 8 per-wave partials for this lane's row (r = lane).
            const float* pp = &s_part[buf][0];
            float sum = xv;
            #pragma unroll
            for (int k = 0; k < 8; ++k) sum += pp[k * 64 + lane];

            // Gather the 4 gates of h-index t_j (rows t_j, +16, +32, +48).
            float gi = __shfl(sum, t_j + 0,  64);
            float gf = __shfl(sum, t_j + 16, 64);
            float gg = __shfl(sum, t_j + 32, 64);
            float go = __shfl(sum, t_j + 48, 64);

            float iv = fast_sigmoid(gi);
            float fv = fast_sigmoid(gf);
            float ov = fast_sigmoid(go);
            float gv = fast_tanh(gg);
            c_state = fv * c_state + iv * gv;     // identical on the 4 gate-lanes
            float hn = ov * fast_tanh(c_state);

            if (lane < 16) {                      // t_j == lane here
                // Coalesced 16-dword nontemporal stream store of h history.
                __builtin_nontemporal_store(hn, hs + (size_t)t * H_DIM + g * 16 + lane);
                u64 m = ((u64)(tagt + 1) << 32) | (u64)__float_as_uint(hn);
                u64* wp = (((t + 1) & 1) ? slot1 : slot0) + (g * 16 + lane);
                __hip_atomic_store(wp, m, __ATOMIC_RELAXED, __HIP_MEMORY_SCOPE_AGENT);
            }
        }
        // No trailing barrier: s_h is intra-wave; s_part double-buffered —
        // its re-write at t+2 is gated by the barrier at t+1, which wave 0
        // only reaches after finishing its reads of s_part[t&1].
    }
}

// ---------------------------------------------------------------------------
// Phase 3: out = log_softmax(hs @ W_out^T + b_out)
// ---------------------------------------------------------------------------
__global__ __launch_bounds__(256) void out_softmax(
    const float* __restrict__ hs, const float* __restrict__ W_out,
    const float* __restrict__ b_out, float* __restrict__ out)
{
    const int tid = threadIdx.x;
    const int t0  = blockIdx.x * 16;

    __shared__ float s_w[257 * 33];
    __shared__ float s_hs[16 * 33];
    __shared__ float s_o[16 * 257];
    __shared__ float s_red[8];

    float acc[16] = {};
    float acc256 = 0.f;

    for (int k0 = 0; k0 < H_DIM; k0 += 32) {
        for (int idx = tid; idx < 257 * 32; idx += 256) {
            int row = idx >> 5, col = idx & 31;
            s_w[row * 33 + col] = W_out[(size_t)row * H_DIM + k0 + col];
        }
        for (int idx = tid; idx < 16 * 32; idx += 256) {
            int row = idx >> 5, col = idx & 31;
            s_hs[row * 33 + col] = hs[(size_t)(t0 + row) * H_DIM + k0 + col];
        }
        __syncthreads();
        #pragma unroll
        for (int kk = 0; kk < 32; ++kk) {
            float w = s_w[tid * 33 + kk];
            #pragma unroll
            for (int r = 0; r < 16; ++r)
                acc[r] += s_hs[r * 33 + kk] * w;
        }
        if (tid < 16) {
            #pragma unroll
            for (int kk = 0; kk < 32; ++kk)
                acc256 += s_w[256 * 33 + kk] * s_hs[tid * 33 + kk];
        }
        __syncthreads();
    }

    float bias_c = b_out[tid];
    #pragma unroll
    for (int r = 0; r < 16; ++r) s_o[r * 257 + tid] = acc[r] + bias_c;
    if (tid < 16) s_o[tid * 257 + 256] = acc256 + b_out[256];
    __syncthreads();

    const int lane = tid & 63, wid = tid >> 6;
    for (int r = 0; r < 16; ++r) {
        float v  = s_o[r * 257 + tid];
        float vx = (tid == 0) ? s_o[r * 257 + 256] : -INFINITY;
        float m = fmaxf(v, vx);
        #pragma unroll
        for (int off = 32; off > 0; off >>= 1) m = fmaxf(m, __shfl_xor(m, off, 64));
        if (lane == 0) s_red[wid] = m;
        __syncthreads();
        m = fmaxf(fmaxf(s_red[0], s_red[1]), fmaxf(s_red[2], s_red[3]));
        float e = expf(v - m) + ((tid == 0) ? expf(vx - m) : 0.f);
        #pragma unroll
        for (int off = 32; off > 0; off >>= 1) e += __shfl_xor(e, off, 64);
        if (lane == 0) s_red[4 + wid] = e;
        __syncthreads();
        float s = s_red[4] + s_red[5] + s_red[6] + s_red[7];
        float lg = logf(s) + m;
        out[(size_t)(t0 + r) * O_DIM + tid] = v - lg;
        if (tid == 0) out[(size_t)(t0 + r) * O_DIM + 256] = vx - lg;
    }
}

// ---------------------------------------------------------------------------
extern "C" void kernel_launch(void* const* d_in, const int* in_sizes, int n_in,
                              void* d_out, int out_size, void* d_ws, size_t ws_size,
                              hipStream_t stream) {
    (void)in_sizes; (void)n_in; (void)out_size; (void)ws_size;

    const float* stft  = (const float*)d_in[0];
    const float* W_ih  = (const float*)d_in[1];
    const float* W_hh  = (const float*)d_in[2];
    const float* b_ih  = (const float*)d_in[3];
    const float* b_hh  = (const float*)d_in[4];
    const float* W_out = (const float*)d_in[5];
    const float* b_out = (const float*)d_in[6];
    float* out = (float*)d_out;

    char* ws = (char*)d_ws;
    u64* msg  = (u64*)ws;
    float* xg = (float*)(ws + WS_XG_OFF);
    float* hs = (float*)(ws + WS_HS_OFF);

    // Zero both msg slots (ws is re-poisoned to 0xAA before every launch).
    // tag 0 + h 0 is exactly the t=0 initial state.
    (void)hipMemsetAsync(ws, 0, 8192, stream);

    xgate_gemm<<<dim3(G4 / 64, T_STEPS / 64), 256, 0, stream>>>(
        stft, W_ih, b_ih, b_hh, xg);
    lstm_seq<<<32, 512, 0, stream>>>(W_hh, xg, hs, msg);
    out_softmax<<<T_STEPS / 16, 256, 0, stream>>>(hs, W_out, b_out, out);
}